// Round 1
// 9460.178 us; speedup vs baseline: 1.2351x; 1.2351x over previous
//
#include <hip/hip_runtime.h>
#include <stdint.h>

typedef unsigned short u16;
typedef __attribute__((ext_vector_type(8))) short short8;
typedef __attribute__((ext_vector_type(4))) float f32x4;

__device__ __forceinline__ float bf2f(u16 u){
    union { uint32_t i; float f; } x; x.i = ((uint32_t)u)<<16; return x.f;
}
__device__ __forceinline__ u16 f2bf(float f){
    union { float f; uint32_t i; } x; x.f = f;
    uint32_t u = x.i + 0x7FFFu + ((x.i>>16)&1u);   // RNE
    return (u16)(u>>16);
}
// v = hi + mid + lo, each bf16; residuals are exact f32 subtractions
__device__ __forceinline__ void split3(float v, u16& hi, u16& mid, u16& lo){
    hi = f2bf(v);            float r  = v - bf2f(hi);
    mid = f2bf(r);           float r2 = r - bf2f(mid);
    lo = f2bf(r2);
}
__device__ __forceinline__ void split2(float v, u16& hi, u16& mid){
    hi = f2bf(v);  mid = f2bf(v - bf2f(hi));
}

#define MFMA __builtin_amdgcn_mfma_f32_16x16x32_bf16
// Agent-scope relaxed atomics -> global_load/store with sc0 sc1: bypass L1/L2,
// coherent at the die-level L3 (correct for any block->XCD placement), and
// crucially NO buffer_wbl2 / buffer_inv cache nukes (no fences needed: the
// per-wave s_waitcnt vmcnt(0) before the counter post is the release).
#define AL64(p)   __hip_atomic_load((const unsigned long long*)(p), __ATOMIC_RELAXED, __HIP_MEMORY_SCOPE_AGENT)
#define AL16(p)   __hip_atomic_load((p), __ATOMIC_RELAXED, __HIP_MEMORY_SCOPE_AGENT)
#define AS16(p,v) __hip_atomic_store((p), (v), __ATOMIC_RELAXED, __HIP_MEMORY_SCOPE_AGENT)

// ---------------- fused recurrent kernel, near-f32 numerics ----------------
// 256 blocks = 16 groups (16 batch rows) x 16 col-blocks (32 cols).
// Wave wv: gate = wv>>1 (0: c-gate/W_c, 1: a-gate/W_a), half = wv&1 (16-col half).
// Weights resident in VGPRs as 2-way bf16 (hi+mid, rep err 2^-17).
// h carried as 3-way bf16 (rep err 2^-26), double-buffered in ws, exchanged
// through L3 via relaxed agent atomics (no threadfence).
// Per-step pipeline: hGEMM(t) -> stash -> epilogue(t) writes h_{t+1} ->
// per-wave vmcnt(0)+post -> xproj(t+1) (overlaps other blocks' tails) -> spin.
__global__ __launch_bounds__(256,1)
void rec_fused(const float* __restrict__ x,  const float* __restrict__ h0,
               const float* __restrict__ Wc, const float* __restrict__ Wa,
               const float* __restrict__ Uc, const float* __restrict__ Ua, const float* __restrict__ Uh,
               const float* __restrict__ bc, const float* __restrict__ ba, const float* __restrict__ bh,
               float* __restrict__ out,
               u16* __restrict__ hhi, u16* __restrict__ hmd, u16* __restrict__ hlo,
               unsigned int* __restrict__ cnt)
{
    const int tid  = threadIdx.x;
    const int bid  = blockIdx.x;
    const int g    = bid & 15;      // batch-row group (blocks g+16k land on XCD g&7)
    const int cb   = bid >> 4;      // col-block 0..15
    const int lane = tid & 63;
    const int wv   = tid >> 6;
    const int gate = wv >> 1;
    const int half = wv & 1;
    const int n16  = lane & 15;
    const int q    = lane >> 4;
    const int b0   = g * 16;
    const int j0   = cb * 32;
    const int jw   = j0 + half*16;

    __shared__ float accC[2][16][17];        // +1 pad: kill 4-way bank conflict
    __shared__ float accA[2][16][17];
    __shared__ float xpre[3][2][16][17];

    // ---- resident weight fragments, 2-way split ----
    // B-operand: lane n16 = output col jw+n16, k = kk*32 + q*8 + i
    const float* Wg = gate ? Wa : Wc;
    short8 wfh[16], wfm[16];
    #pragma unroll
    for (int kk=0;kk<16;++kk){
        const float* p = Wg + (size_t)(jw + n16)*512 + kk*32 + q*8;
        #pragma unroll
        for (int i=0;i<8;++i){ u16 a,b; split2(p[i],a,b); wfh[kk][i]=(short)a; wfm[kk][i]=(short)b; }
    }
    const float* U0 = gate ? Ua : Uc;    // primary U for this gate
    short8 u0h[8], u0m[8], u1h[8], u1m[8];
    #pragma unroll
    for (int kk=0;kk<8;++kk){
        const float* p = U0 + (size_t)(jw + n16)*256 + kk*32 + q*8;
        #pragma unroll
        for (int i=0;i<8;++i){ u16 a,b; split2(p[i],a,b); u0h[kk][i]=(short)a; u0m[kk][i]=(short)b; }
        const float* p2 = Uh + (size_t)(jw + n16)*256 + kk*32 + q*8;
        #pragma unroll
        for (int i=0;i<8;++i){ u16 a,b; split2(p2[i],a,b); u1h[kk][i]=(short)a; u1m[kk][i]=(short)b; }
    }

    // ---- init h buffer 0: 3-way split of f32 h0 (coherent stores) ----
    if (cb == 0) {
        for (int i = tid; i < 16*512; i += 256) {
            int m = i >> 9, k = i & 511;
            size_t o = (size_t)(b0+m)*512 + k;
            u16 a,b,c; split3(h0[o], a,b,c);
            AS16(hhi+o,a); AS16(hmd+o,b); AS16(hlo+o,c);
        }
    }
    unsigned int* cg = cnt + g*32;   // 128B-spaced per-group counters

    // x projections for timestep tt: A[m=n16][k=q*8+i], x split 3-way on the fly
    auto xproj = [&](int tt, f32x4& o0, f32x4& o1){
        f32x4 z = (f32x4){0.f,0.f,0.f,0.f};
        f32x4 p0=z,p1=z,p2=z,p3=z, q0=z,q1=z,q2=z,q3=z;
        #pragma unroll
        for (int kk=0;kk<8;++kk){
            const float* xp = x + ((size_t)tt*256 + b0 + n16)*256 + kk*32 + q*8;
            short8 xh_, xm_, xl_;
            #pragma unroll
            for (int i=0;i<8;++i){ u16 a,b,c; split3(xp[i],a,b,c); xh_[i]=(short)a; xm_[i]=(short)b; xl_[i]=(short)c; }
            p0 = MFMA(xh_, u0h[kk], p0, 0,0,0);
            p1 = MFMA(xh_, u0m[kk], p1, 0,0,0);
            p2 = MFMA(xm_, u0h[kk], p2, 0,0,0);
            p3 = MFMA(xm_, u0m[kk], p3, 0,0,0);
            p0 = MFMA(xl_, u0h[kk], p0, 0,0,0);
            if (gate == 1) {          // wave-uniform
                q0 = MFMA(xh_, u1h[kk], q0, 0,0,0);
                q1 = MFMA(xh_, u1m[kk], q1, 0,0,0);
                q2 = MFMA(xm_, u1h[kk], q2, 0,0,0);
                q3 = MFMA(xm_, u1m[kk], q3, 0,0,0);
                q0 = MFMA(xl_, u1h[kk], q0, 0,0,0);
            }
        }
        #pragma unroll
        for (int r=0;r<4;++r){ o0[r]=(p0[r]+p1[r])+(p2[r]+p3[r]); o1[r]=(q0[r]+q1[r])+(q2[r]+q3[r]); }
    };

    // ---- prologue: per-wave release + post, overlap xproj(0) with the wait ----
    asm volatile("s_waitcnt vmcnt(0)" ::: "memory");    // own wave's init stores done @L3
    if (lane == 0)
        __hip_atomic_fetch_add(cg, 1u, __ATOMIC_RELAXED, __HIP_MEMORY_SCOPE_AGENT);

    const int   jme = j0 + half*16 + n16;
    const float bcv = bc[jme], bav = ba[jme], bhv = bh[jme];   // biases hoisted

    f32x4 xp0, xp1;
    xproj(0, xp0, xp1);

    unsigned int target = 64u;      // counts WAVES: 16 blocks x 4 waves per phase
    if (lane == 0) {
        while (__hip_atomic_load(cg, __ATOMIC_RELAXED, __HIP_MEMORY_SCOPE_AGENT) < target)
            __builtin_amdgcn_s_sleep(2);
    }
    __syncthreads();

    float hfr0 = 0.f, hfr1 = 0.f;   // register-carried h (split-sum) for epilogue

    #pragma unroll 1
    for (int t = 0; t < 512; ++t) {
        const size_t cur = (size_t)(t & 1) * (256*512);
        const size_t nxt = (size_t)((t+1) & 1) * (256*512);

        // ---- h GEMM: batch-issue all 96 coherent loads, then 5-chain MFMA ----
        short8 Ph[16], Pm[16], Pl[16];
        #pragma unroll
        for (int kk=0;kk<16;++kk){
            size_t o = cur + (size_t)(b0 + n16)*512 + kk*32 + q*8;
            union { unsigned long long u[2]; short8 v; } th_, tm_, tl_;
            th_.u[0]=AL64(hhi+o); th_.u[1]=AL64(hhi+o+4);
            tm_.u[0]=AL64(hmd+o); tm_.u[1]=AL64(hmd+o+4);
            tl_.u[0]=AL64(hlo+o); tl_.u[1]=AL64(hlo+o+4);
            Ph[kk]=th_.v; Pm[kk]=tm_.v; Pl[kk]=tl_.v;
        }
        f32x4 z = (f32x4){0.f,0.f,0.f,0.f};
        f32x4 a0=z,a1=z,a2=z,a3=z;
        #pragma unroll
        for (int kk=0;kk<16;++kk){
            a0 = MFMA(Ph[kk], wfh[kk], a0, 0,0,0);
            a1 = MFMA(Ph[kk], wfm[kk], a1, 0,0,0);
            a2 = MFMA(Pm[kk], wfh[kk], a2, 0,0,0);
            a3 = MFMA(Pm[kk], wfm[kk], a3, 0,0,0);
            a1 = MFMA(Pl[kk], wfh[kk], a1, 0,0,0);
        }

        // ---- stash in LDS (C/D: row=q*4+r, col=n16); xp holds xproj(t) ----
        #pragma unroll
        for (int r=0;r<4;++r) {
            float v = (a0[r]+a1[r]) + (a2[r]+a3[r]);
            if (gate == 0) accC[half][q*4+r][n16] = v;
            else           accA[half][q*4+r][n16] = v;
            xpre[gate][half][q*4+r][n16] = xp0[r];
            if (gate == 1) xpre[2][half][q*4+r][n16] = xp1[r];
        }
        __syncthreads();

        // ---- epilogue: each wave covers (col-half wv&1, rows q*4+gate*2+e) ----
        const int rp = gate * 2;
        #pragma unroll
        for (int e=0;e<2;++e) {
            const int row = q*4 + rp + e;
            const int b   = b0 + row;
            const float cpre = accC[half][row][n16];
            const float apre = accA[half][row][n16];
            const float xc = xpre[0][half][row][n16] + bcv;
            const float xa = xpre[1][half][row][n16] + bav;
            const float xh = xpre[2][half][row][n16] + bhv;
            const size_t hb = (size_t)b*512 + jme;

            float hf;
            if (t == 0)   // cur == 0: read the init split; afterwards carried in regs
                hf = bf2f(AL16(hhi+hb)) + (bf2f(AL16(hmd+hb)) + bf2f(AL16(hlo+hb)));
            else
                hf = e ? hfr1 : hfr0;

            const float cv = 1.f/(1.f + __expf(-(cpre + xc)));        // sigmoid
            const float av = 2.f/(1.f + __expf(-2.f*(apre + xa)));    // 1 + tanh
            const float zz = xh + av*hf;
            const float th = 2.f/(1.f + __expf(-2.f*zz)) - 1.f;       // tanh
            const float hn = cv*hf + (1.f - cv)*th;

            u16 sh, sm, sl; split3(hn, sh, sm, sl);
            AS16(hhi+nxt+hb, sh); AS16(hmd+nxt+hb, sm); AS16(hlo+nxt+hb, sl);
            const float hrep = bf2f(sh) + (bf2f(sm) + bf2f(sl));      // exact split-sum
            if (e) hfr1 = hrep; else hfr0 = hrep;

            __builtin_nontemporal_store(hn, &out[((size_t)t*256 + b)*512 + jme]); // y_seq
            if (t == 511) out[(size_t)67108864 + hb] = hn;            // hn (f32)
        }

        // ---- per-wave release + post; overlap next xproj with other blocks ----
        asm volatile("s_waitcnt vmcnt(0)" ::: "memory");   // own h stores @L3
        if (lane == 0)
            __hip_atomic_fetch_add(cg, 1u, __ATOMIC_RELAXED, __HIP_MEMORY_SCOPE_AGENT);

        const int tn = (t < 511) ? t+1 : 511;              // last iter: dummy (valid mem)
        xproj(tn, xp0, xp1);

        target += 64u;
        if (lane == 0) {
            while (__hip_atomic_load(cg, __ATOMIC_RELAXED, __HIP_MEMORY_SCOPE_AGENT) < target)
                __builtin_amdgcn_s_sleep(2);
        }
        __syncthreads();   // join waves + protect LDS before next stash
    }
}

// ---------------- launch ----------------
extern "C" void kernel_launch(void* const* d_in, const int* in_sizes, int n_in,
                              void* d_out, int out_size, void* d_ws, size_t ws_size,
                              hipStream_t stream)
{
    (void)in_sizes; (void)n_in; (void)out_size; (void)ws_size;
    const float* x  = (const float*)d_in[0];
    const float* h0 = (const float*)d_in[1];
    const float* Uc = (const float*)d_in[2];
    const float* Wc = (const float*)d_in[3];
    const float* bc = (const float*)d_in[4];
    const float* Ua = (const float*)d_in[5];
    const float* Wa = (const float*)d_in[6];
    const float* ba = (const float*)d_in[7];
    const float* Uh = (const float*)d_in[8];
    const float* bh = (const float*)d_in[9];
    float* out = (float*)d_out;

    char* ws = (char*)d_ws;
    unsigned int* cnt = (unsigned int*)ws;                 // 16 counters, 128B apart
    u16* hhi = (u16*)(ws + 2048);                          // each: 2 x (256,512) bf16
    u16* hmd = hhi + (size_t)2*256*512;
    u16* hlo = hmd + (size_t)2*256*512;
    // total ws use: 2048 + 3*2*262144*2 = ~3.1 MB

    hipMemsetAsync(cnt, 0, 2048, stream);                  // counters MUST start at 0

    rec_fused<<<256, 256, 0, stream>>>(x, h0, Wc, Wa, Uc, Ua, Uh, bc, ba, bh,
                                       out, hhi, hmd, hlo, cnt);
}

// Round 2
// 5303.805 us; speedup vs baseline: 2.2031x; 1.7837x over previous
//
#include <hip/hip_runtime.h>
#include <stdint.h>

typedef unsigned short u16;
typedef __attribute__((ext_vector_type(8))) short short8;
typedef __attribute__((ext_vector_type(4))) float f32x4;

__device__ __forceinline__ float bf2f(u16 u){
    union { uint32_t i; float f; } x; x.i = ((uint32_t)u)<<16; return x.f;
}
__device__ __forceinline__ u16 f2bf(float f){
    union { float f; uint32_t i; } x; x.f = f;
    uint32_t u = x.i + 0x7FFFu + ((x.i>>16)&1u);   // RNE
    return (u16)(u>>16);
}
// v = hi + mid + lo, each bf16; residuals are exact f32 subtractions
__device__ __forceinline__ void split3(float v, u16& hi, u16& mid, u16& lo){
    hi = f2bf(v);            float r  = v - bf2f(hi);
    mid = f2bf(r);           float r2 = r - bf2f(mid);
    lo = f2bf(r2);
}
__device__ __forceinline__ void split2(float v, u16& hi, u16& mid){
    hi = f2bf(v);  mid = f2bf(v - bf2f(hi));
}

#define MFMA __builtin_amdgcn_mfma_f32_16x16x32_bf16
// Agent-scope relaxed atomics -> L1/L2-bypassing, coherent at die-level L3.
// No fences: per-wave s_waitcnt vmcnt(0) before the counter post is the release.
#define AL64(p)   __hip_atomic_load((const unsigned long long*)(p), __ATOMIC_RELAXED, __HIP_MEMORY_SCOPE_AGENT)
#define AL16(p)   __hip_atomic_load((p), __ATOMIC_RELAXED, __HIP_MEMORY_SCOPE_AGENT)
#define AS16(p,v) __hip_atomic_store((p), (v), __ATOMIC_RELAXED, __HIP_MEMORY_SCOPE_AGENT)

// ---------------- fused recurrent kernel, near-f32 numerics ----------------
// 256 blocks = 16 groups (16 batch rows) x 16 col-blocks (32 cols).
// h carried as 3-plane bf16 split (hi/mid/lo), double-buffered in ws, stored in
// MFMA-FRAGMENT ORDER: elem (plane a, row, col) at
//   p = a*8192 + (kk*64 + q*16 + row)*8 + i,  kk=col>>5, q=(col>>3)&3, i=col&7
// so the consumer's 48KB tile is loaded cooperatively with perfectly-coalesced
// 8B/lane contiguous loads (128B-efficient L3 transactions), staged once in LDS,
// and ds_read_b128 at lane*16 gives conflict-free A-fragments for all 4 waves.
__global__ __launch_bounds__(256,1)
void rec_fused(const float* __restrict__ x,  const float* __restrict__ h0,
               const float* __restrict__ Wc, const float* __restrict__ Wa,
               const float* __restrict__ Uc, const float* __restrict__ Ua, const float* __restrict__ Uh,
               const float* __restrict__ bc, const float* __restrict__ ba, const float* __restrict__ bh,
               float* __restrict__ out,
               u16* __restrict__ hbuf,
               unsigned int* __restrict__ cnt)
{
    const int tid  = threadIdx.x;
    const int bid  = blockIdx.x;
    const int g    = bid & 15;      // batch-row group (blocks g+16k land on XCD g&7)
    const int cb   = bid >> 4;      // col-block 0..15
    const int lane = tid & 63;
    const int wv   = tid >> 6;
    const int gate = wv >> 1;
    const int half = wv & 1;
    const int n16  = lane & 15;
    const int q    = lane >> 4;
    const int b0   = g * 16;
    const int j0   = cb * 32;
    const int jw   = j0 + half*16;

    __shared__ float accC[2][16][17];        // +1 pad: kill bank conflicts
    __shared__ float accA[2][16][17];
    __shared__ float xpre[3][2][16][17];
    __shared__ u16  hstage[3*16*512];        // 48KB frag-ordered h tile

    // ---- resident weight fragments, 2-way split ----
    const float* Wg = gate ? Wa : Wc;
    short8 wfh[16], wfm[16];
    #pragma unroll
    for (int kk=0;kk<16;++kk){
        const float* p = Wg + (size_t)(jw + n16)*512 + kk*32 + q*8;
        #pragma unroll
        for (int i=0;i<8;++i){ u16 a,b; split2(p[i],a,b); wfh[kk][i]=(short)a; wfm[kk][i]=(short)b; }
    }
    const float* U0 = gate ? Ua : Uc;    // primary U for this gate
    short8 u0h[8], u0m[8], u1h[8], u1m[8];
    #pragma unroll
    for (int kk=0;kk<8;++kk){
        const float* p = U0 + (size_t)(jw + n16)*256 + kk*32 + q*8;
        #pragma unroll
        for (int i=0;i<8;++i){ u16 a,b; split2(p[i],a,b); u0h[kk][i]=(short)a; u0m[kk][i]=(short)b; }
        const float* p2 = Uh + (size_t)(jw + n16)*256 + kk*32 + q*8;
        #pragma unroll
        for (int i=0;i<8;++i){ u16 a,b; split2(p2[i],a,b); u1h[kk][i]=(short)a; u1m[kk][i]=(short)b; }
    }

    // ---- per-group double-buffered frag-ordered h regions ----
    u16* reg0 = hbuf + (size_t)(g*2 + 0) * 24576;
    u16* reg1 = hbuf + (size_t)(g*2 + 1) * 24576;

    // ---- init buffer 0: 3-way split of f32 h0, frag layout ----
    if (cb == 0) {
        for (int idx = tid; idx < 16*512; idx += 256) {
            int m = idx >> 9, k = idx & 511;
            u16 a,b,c; split3(h0[(size_t)(b0+m)*512 + k], a,b,c);
            int pp = (((k>>5)*64 + ((k>>3)&3)*16 + m)<<3) + (k&7);
            AS16(reg0 + pp, a); AS16(reg0 + 8192 + pp, b); AS16(reg0 + 16384 + pp, c);
        }
    }
    unsigned int* cg = cnt + g*32;   // 128B-spaced per-group counters

    // x projections for timestep tt: A[m=n16][k=q*8+i], x split 3-way on the fly
    auto xproj = [&](int tt, f32x4& o0, f32x4& o1){
        f32x4 z = (f32x4){0.f,0.f,0.f,0.f};
        f32x4 p0=z,p1=z,p2=z,p3=z, q0=z,q1=z,q2=z,q3=z;
        #pragma unroll
        for (int kk=0;kk<8;++kk){
            const float* xp = x + ((size_t)tt*256 + b0 + n16)*256 + kk*32 + q*8;
            short8 xh_, xm_, xl_;
            #pragma unroll
            for (int i=0;i<8;++i){ u16 a,b,c; split3(xp[i],a,b,c); xh_[i]=(short)a; xm_[i]=(short)b; xl_[i]=(short)c; }
            p0 = MFMA(xh_, u0h[kk], p0, 0,0,0);
            p1 = MFMA(xh_, u0m[kk], p1, 0,0,0);
            p2 = MFMA(xm_, u0h[kk], p2, 0,0,0);
            p3 = MFMA(xm_, u0m[kk], p3, 0,0,0);
            p0 = MFMA(xl_, u0h[kk], p0, 0,0,0);
            if (gate == 1) {          // wave-uniform
                q0 = MFMA(xh_, u1h[kk], q0, 0,0,0);
                q1 = MFMA(xh_, u1m[kk], q1, 0,0,0);
                q2 = MFMA(xm_, u1h[kk], q2, 0,0,0);
                q3 = MFMA(xm_, u1m[kk], q3, 0,0,0);
                q0 = MFMA(xl_, u1h[kk], q0, 0,0,0);
            }
        }
        #pragma unroll
        for (int r=0;r<4;++r){ o0[r]=(p0[r]+p1[r])+(p2[r]+p3[r]); o1[r]=(q0[r]+q1[r])+(q2[r]+q3[r]); }
    };

    // ---- prologue: per-wave release + post, overlap xproj(0) with the wait ----
    asm volatile("s_waitcnt vmcnt(0)" ::: "memory");    // own init stores @L3
    if (lane == 0)
        __hip_atomic_fetch_add(cg, 1u, __ATOMIC_RELAXED, __HIP_MEMORY_SCOPE_AGENT);

    const int   jme = j0 + half*16 + n16;
    const float bcv = bc[jme], bav = ba[jme], bhv = bh[jme];   // biases hoisted
    // writer-side frag offset base for my column jme (kk = cb for this block)
    const int wpp0 = ((cb*64 + (half*2 + (n16>>3))*16)<<3) + (n16&7);

    f32x4 xp0, xp1;
    xproj(0, xp0, xp1);

    unsigned int target = 64u;      // counts WAVES: 16 blocks x 4 waves per phase
    if (lane == 0) {
        while (__hip_atomic_load(cg, __ATOMIC_RELAXED, __HIP_MEMORY_SCOPE_AGENT) < target)
            __builtin_amdgcn_s_sleep(2);
    }
    __syncthreads();

    float hfr0 = 0.f, hfr1 = 0.f;   // register-carried h (split-sum) for epilogue
    const int rp = gate * 2;

    #pragma unroll 1
    for (int t = 0; t < 512; ++t) {
        u16* curp = (t & 1) ? reg1 : reg0;
        u16* nxtp = (t & 1) ? reg0 : reg1;

        // ---- cooperative coalesced stage: 48KB frag-ordered h -> LDS ----
        {
            unsigned long long d0[12], d1[12];
            #pragma unroll
            for (int it=0; it<12; ++it){
                const u16* s = curp + (size_t)(it*256 + tid)*8;
                d0[it] = AL64(s); d1[it] = AL64(s+4);
            }
            #pragma unroll
            for (int it=0; it<12; ++it){
                union { unsigned long long u[2]; short8 v; } w;
                w.u[0] = d0[it]; w.u[1] = d1[it];
                *(short8*)&hstage[(it*256 + tid)*8] = w.v;
            }
        }
        __syncthreads();

        // ---- h GEMM: conflict-free frag reads + 5-chain MFMA ----
        f32x4 z = (f32x4){0.f,0.f,0.f,0.f};
        f32x4 a0=z,a1=z,a2=z,a3=z;
        #pragma unroll
        for (int kk=0;kk<16;++kk){
            const int off = (kk*64 + lane)*8;
            short8 hh = *(const short8*)&hstage[off];
            short8 hm = *(const short8*)&hstage[8192  + off];
            short8 hl = *(const short8*)&hstage[16384 + off];
            a0 = MFMA(hh, wfh[kk], a0, 0,0,0);
            a1 = MFMA(hh, wfm[kk], a1, 0,0,0);
            a2 = MFMA(hm, wfh[kk], a2, 0,0,0);
            a3 = MFMA(hm, wfm[kk], a3, 0,0,0);
            a1 = MFMA(hl, wfh[kk], a1, 0,0,0);
        }

        // ---- stash in LDS (C/D: row=q*4+r, col=n16); xp holds xproj(t) ----
        #pragma unroll
        for (int r=0;r<4;++r) {
            float v = (a0[r]+a1[r]) + (a2[r]+a3[r]);
            if (gate == 0) accC[half][q*4+r][n16] = v;
            else           accA[half][q*4+r][n16] = v;
            xpre[gate][half][q*4+r][n16] = xp0[r];
            if (gate == 1) xpre[2][half][q*4+r][n16] = xp1[r];
        }
        __syncthreads();

        // ---- epilogue: each wave covers (col-half wv&1, rows q*4+gate*2+e) ----
        float hn_e[2];
        #pragma unroll
        for (int e=0;e<2;++e) {
            const int row = q*4 + rp + e;
            const float cpre = accC[half][row][n16];
            const float apre = accA[half][row][n16];
            const float xc = xpre[0][half][row][n16] + bcv;
            const float xa = xpre[1][half][row][n16] + bav;
            const float xh = xpre[2][half][row][n16] + bhv;
            const int pp = wpp0 + row*8;

            float hf;
            if (t == 0)   // cur == buf0: read the init split; afterwards reg-carried
                hf = bf2f(AL16(curp+pp)) + (bf2f(AL16(curp+8192+pp)) + bf2f(AL16(curp+16384+pp)));
            else
                hf = e ? hfr1 : hfr0;

            const float cv = 1.f/(1.f + __expf(-(cpre + xc)));        // sigmoid
            const float av = 2.f/(1.f + __expf(-2.f*(apre + xa)));    // 1 + tanh
            const float zz = xh + av*hf;
            const float th = 2.f/(1.f + __expf(-2.f*zz)) - 1.f;       // tanh
            const float hn = cv*hf + (1.f - cv)*th;

            u16 sh, sm, sl; split3(hn, sh, sm, sl);
            AS16(nxtp+pp, sh); AS16(nxtp+8192+pp, sm); AS16(nxtp+16384+pp, sl);
            const float hrep = bf2f(sh) + (bf2f(sm) + bf2f(sl));      // exact split-sum
            if (e) hfr1 = hrep; else hfr0 = hrep;
            hn_e[e] = hn;
        }

        // ---- drain h stores, post (y stores kept OFF the critical path) ----
        asm volatile("s_waitcnt vmcnt(0)" ::: "memory");
        if (lane == 0)
            __hip_atomic_fetch_add(cg, 1u, __ATOMIC_RELAXED, __HIP_MEMORY_SCOPE_AGENT);

        // ---- y stores (HBM, nontemporal) after the post ----
        #pragma unroll
        for (int e=0;e<2;++e) {
            const int b = b0 + q*4 + rp + e;
            __builtin_nontemporal_store(hn_e[e], &out[((size_t)t*256 + b)*512 + jme]);
            if (t == 511) out[(size_t)67108864 + (size_t)b*512 + jme] = hn_e[e];
        }

        // ---- overlap next xproj with other blocks' tails, then spin ----
        const int tn = (t < 511) ? t+1 : 511;              // last iter: dummy (valid mem)
        xproj(tn, xp0, xp1);

        target += 64u;
        if (lane == 0) {
            while (__hip_atomic_load(cg, __ATOMIC_RELAXED, __HIP_MEMORY_SCOPE_AGENT) < target)
                __builtin_amdgcn_s_sleep(2);
        }
        __syncthreads();   // join waves + protect LDS before next stage
    }
}

// ---------------- launch ----------------
extern "C" void kernel_launch(void* const* d_in, const int* in_sizes, int n_in,
                              void* d_out, int out_size, void* d_ws, size_t ws_size,
                              hipStream_t stream)
{
    (void)in_sizes; (void)n_in; (void)out_size; (void)ws_size;
    const float* x  = (const float*)d_in[0];
    const float* h0 = (const float*)d_in[1];
    const float* Uc = (const float*)d_in[2];
    const float* Wc = (const float*)d_in[3];
    const float* bc = (const float*)d_in[4];
    const float* Ua = (const float*)d_in[5];
    const float* Wa = (const float*)d_in[6];
    const float* ba = (const float*)d_in[7];
    const float* Uh = (const float*)d_in[8];
    const float* bh = (const float*)d_in[9];
    float* out = (float*)d_out;

    char* ws = (char*)d_ws;
    unsigned int* cnt = (unsigned int*)ws;                 // 16 counters, 128B apart
    u16* hbuf = (u16*)(ws + 2048);                         // 16 groups x 2 parity x 48KB
    // total ws use: 2048 + 16*2*24576*2B = ~1.58 MB

    hipMemsetAsync(cnt, 0, 2048, stream);                  // counters MUST start at 0

    rec_fused<<<256, 256, 0, stream>>>(x, h0, Wc, Wa, Uc, Ua, Uh, bc, ba, bh,
                                       out, hbuf, cnt);
}

// Round 3
// 3461.575 us; speedup vs baseline: 3.3755x; 1.5322x over previous
//
#include <hip/hip_runtime.h>
#include <stdint.h>

typedef unsigned short u16;
typedef unsigned int u32;
typedef unsigned long long u64;
typedef __attribute__((ext_vector_type(8))) short short8;
typedef __attribute__((ext_vector_type(4))) float f32x4;

__device__ __forceinline__ float bf2f(u16 u){
    union { u32 i; float f; } x; x.i = ((u32)u)<<16; return x.f;
}
__device__ __forceinline__ u16 f2bf(float f){
    union { float f; u32 i; } x; x.f = f;
    u32 u = x.i + 0x7FFFu + ((x.i>>16)&1u);   // RNE
    return (u16)(u>>16);
}
// v = hi + mid + lo, each bf16; residuals are exact f32 subtractions
__device__ __forceinline__ void split3(float v, u16& hi, u16& mid, u16& lo){
    hi = f2bf(v);            float r  = v - bf2f(hi);
    mid = f2bf(r);           float r2 = r - bf2f(mid);
    lo = f2bf(r2);
}
__device__ __forceinline__ void split2(float v, u16& hi, u16& mid){
    hi = f2bf(v);  mid = f2bf(v - bf2f(hi));
}

#define MFMA __builtin_amdgcn_mfma_f32_16x16x32_bf16
// Agent-scope relaxed atomics -> L1/L2-bypassing, coherent at die-level L3.
// Release = per-wave s_waitcnt vmcnt(0) before the slot post. No RMW anywhere:
// each block posts its phase number to its OWN slot; consumers poll 16 slots
// with a single 16-lane load (one L3 line).
#define AL64(p)   __hip_atomic_load((const u64*)(p), __ATOMIC_RELAXED, __HIP_MEMORY_SCOPE_AGENT)
#define AS64(p,v) __hip_atomic_store((u64*)(p), (v), __ATOMIC_RELAXED, __HIP_MEMORY_SCOPE_AGENT)
#define AL16(p)   __hip_atomic_load((p), __ATOMIC_RELAXED, __HIP_MEMORY_SCOPE_AGENT)
#define AS16(p,v) __hip_atomic_store((p), (v), __ATOMIC_RELAXED, __HIP_MEMORY_SCOPE_AGENT)
#define AL32(p)   __hip_atomic_load((p), __ATOMIC_RELAXED, __HIP_MEMORY_SCOPE_AGENT)
#define AS32(p,v) __hip_atomic_store((p), (v), __ATOMIC_RELAXED, __HIP_MEMORY_SCOPE_AGENT)

// ---------------- fused recurrent kernel, near-f32 numerics ----------------
// 256 blocks = 16 groups (16 batch rows) x 16 col-blocks (32 cols).
// h carried as 3-plane bf16 split, double-buffered in ws, frag-ordered:
//   elem(plane a,row,col) at a*8192 + (kk*64 + q*16 + row)*8 + i,
//   kk=col>>5, q=(col>>3)&3, i=col&7.
// Per-step pipeline (all arithmetic identical to prior version):
//   poll(slots) -> issue h loads -> xsplit(t) into LDS (hides h L3 latency)
//   -> hstage -> B1 -> hGEMM(t)+xproj(t) MFMAs -> stash -> B2 -> epilogue
//   -> hcoal -> B3 -> wave0 coalesced h store + drain + post -> prefetch x(t+1)
__global__ __launch_bounds__(256,1)
void rec_fused(const float* __restrict__ x,  const float* __restrict__ h0,
               const float* __restrict__ Wc, const float* __restrict__ Wa,
               const float* __restrict__ Uc, const float* __restrict__ Ua, const float* __restrict__ Uh,
               const float* __restrict__ bc, const float* __restrict__ ba, const float* __restrict__ bh,
               float* __restrict__ out,
               u16* __restrict__ hbuf,
               u32* __restrict__ cnt)
{
    const int tid  = threadIdx.x;
    const int bid  = blockIdx.x;
    const int g    = bid & 15;      // batch-row group (blocks g+16k land on XCD g&7)
    const int cb   = bid >> 4;      // col-block 0..15
    const int lane = tid & 63;
    const int wv   = tid >> 6;
    const int gate = wv >> 1;
    const int half = wv & 1;
    const int n16  = lane & 15;
    const int q    = lane >> 4;
    const int b0   = g * 16;
    const int j0   = cb * 32;
    const int jw   = j0 + half*16;

    __shared__ float accC[2][16][17];
    __shared__ float accA[2][16][17];
    __shared__ float xpre[3][2][16][17];
    __shared__ u16  hstage[3*8192];      // 48KB frag-ordered h tile
    __shared__ u16  xstage[3*4096];      // 24KB frag-ordered x split (t)
    __shared__ u16  hcoal[3*512];        // 3KB coalescing buffer for h stores

    // ---- resident weight fragments, 2-way split ----
    const float* Wg = gate ? Wa : Wc;
    short8 wfh[16], wfm[16];
    #pragma unroll
    for (int kk=0;kk<16;++kk){
        const float* p = Wg + (size_t)(jw + n16)*512 + kk*32 + q*8;
        #pragma unroll
        for (int i=0;i<8;++i){ u16 a,b; split2(p[i],a,b); wfh[kk][i]=(short)a; wfm[kk][i]=(short)b; }
    }
    const float* U0 = gate ? Ua : Uc;    // primary U for this gate
    short8 u0h[8], u0m[8], u1h[8], u1m[8];
    #pragma unroll
    for (int kk=0;kk<8;++kk){
        const float* p = U0 + (size_t)(jw + n16)*256 + kk*32 + q*8;
        #pragma unroll
        for (int i=0;i<8;++i){ u16 a,b; split2(p[i],a,b); u0h[kk][i]=(short)a; u0m[kk][i]=(short)b; }
        const float* p2 = Uh + (size_t)(jw + n16)*256 + kk*32 + q*8;
        #pragma unroll
        for (int i=0;i<8;++i){ u16 a,b; split2(p2[i],a,b); u1h[kk][i]=(short)a; u1m[kk][i]=(short)b; }
    }

    // ---- per-group double-buffered frag-ordered h regions ----
    u16* reg0 = hbuf + (size_t)(g*2 + 0) * 24576;
    u16* reg1 = hbuf + (size_t)(g*2 + 1) * 24576;

    // ---- init buffer 0: 3-way split of f32 h0, frag layout ----
    if (cb == 0) {
        for (int idx = tid; idx < 16*512; idx += 256) {
            int m = idx >> 9, k = idx & 511;
            u16 a,b,c; split3(h0[(size_t)(b0+m)*512 + k], a,b,c);
            int pp = (((k>>5)*64 + ((k>>3)&3)*16 + m)<<3) + (k&7);
            AS16(reg0 + pp, a); AS16(reg0 + 8192 + pp, b); AS16(reg0 + 16384 + pp, c);
        }
    }
    u32* sg = cnt + g*32;    // 16 u32 slots (one 64B line), groups 128B apart

    // ---- prologue: drain init stores, then post phase 1 to own slot ----
    asm volatile("s_waitcnt vmcnt(0)" ::: "memory");
    __syncthreads();
    if (tid == 0) AS32(sg + cb, 1u);

    const int   jme = j0 + half*16 + n16;
    const int   jl  = half*16 + n16;                           // col within block
    const float bcv = bc[jme], bav = ba[jme], bhv = bh[jme];   // biases hoisted
    // frag offset base for my column jme (kk = cb for this block)
    const int wpp0 = ((cb*64 + (half*2 + (n16>>3))*16)<<3) + (n16&7);

    // ---- x prefetch: thread owns row xrow, cols xc0..xc0+15 of x(t) ----
    const int xrow = tid >> 4;
    const int xc0  = (tid & 15) * 16;
    f32x4 xr0, xr1, xr2, xr3;
    {
        const float* xp = x + ((size_t)0*256 + b0 + xrow)*256 + xc0;
        xr0 = *(const f32x4*)(xp);     xr1 = *(const f32x4*)(xp+4);
        xr2 = *(const f32x4*)(xp+8);   xr3 = *(const f32x4*)(xp+12);
    }

    float hfr0 = 0.f, hfr1 = 0.f;   // register-carried h (split-sum) for epilogue
    const int rp = gate * 2;

    #pragma unroll 1
    for (int t = 0; t < 512; ++t) {
        u16* curp = (t & 1) ? reg1 : reg0;
        u16* nxtp = (t & 1) ? reg0 : reg1;

        // ---- poll: all 16 blocks of the group at phase >= t+1 ----
        {
            const u32 need = (u32)t + 1u;
            for (;;) {
                u32 sv = need;
                if (lane < 16) sv = AL32(sg + lane);
                if (__all((int)(sv >= need))) break;
                __builtin_amdgcn_s_sleep(1);
            }
        }
        asm volatile("" ::: "memory");   // no hoisting of loads above the poll

        // ---- issue the 24 coherent h loads (latency hidden under xsplit) ----
        u64 d0[12], d1[12];
        #pragma unroll
        for (int it=0; it<12; ++it){
            const u16* s = curp + (size_t)(it*256 + tid)*8;
            d0[it] = AL64(s); d1[it] = AL64(s+4);
        }

        // ---- cooperative xsplit(t): 16 split3/thread -> frag-ordered LDS ----
        #pragma unroll
        for (int jh=0; jh<2; ++jh){
            short8 ah, am, al;
            const f32x4 va = jh ? xr2 : xr0;
            const f32x4 vb = jh ? xr3 : xr1;
            #pragma unroll
            for (int j=0;j<8;++j){
                float v = (j<4) ? va[j] : vb[j-4];
                u16 a,b,c; split3(v, a,b,c);
                ah[j]=(short)a; am[j]=(short)b; al[j]=(short)c;
            }
            const int c  = xc0 + jh*8;
            const int ix = ((c>>5)*64 + ((c>>3)&3)*16 + xrow)*8;
            *(short8*)&xstage[        ix] = ah;
            *(short8*)&xstage[4096 +  ix] = am;
            *(short8*)&xstage[8192 +  ix] = al;
        }

        // ---- land h into LDS ----
        #pragma unroll
        for (int it=0; it<12; ++it){
            union { u64 u[2]; short8 v; } w;
            w.u[0] = d0[it]; w.u[1] = d1[it];
            *(short8*)&hstage[(it*256 + tid)*8] = w.v;
        }
        __syncthreads();                                   // B1

        // ---- hGEMM(t): 5 chains ----
        f32x4 z = (f32x4){0.f,0.f,0.f,0.f};
        f32x4 a0=z,a1=z,a2=z,a3=z;
        #pragma unroll
        for (int kk=0;kk<16;++kk){
            const int off = (kk*64 + lane)*8;
            short8 hh = *(const short8*)&hstage[off];
            short8 hm = *(const short8*)&hstage[8192  + off];
            short8 hl = *(const short8*)&hstage[16384 + off];
            a0 = MFMA(hh, wfh[kk], a0, 0,0,0);
            a1 = MFMA(hh, wfm[kk], a1, 0,0,0);
            a2 = MFMA(hm, wfh[kk], a2, 0,0,0);
            a3 = MFMA(hm, wfm[kk], a3, 0,0,0);
            a1 = MFMA(hl, wfh[kk], a1, 0,0,0);
        }
        // ---- xproj(t) from xstage: same chains as before ----
        f32x4 p0=z,p1=z,p2=z,p3=z, q0=z,q1=z,q2=z,q3=z;
        #pragma unroll
        for (int kk=0;kk<8;++kk){
            const int off = (kk*64 + lane)*8;
            short8 xh_ = *(const short8*)&xstage[off];
            short8 xm_ = *(const short8*)&xstage[4096 + off];
            short8 xl_ = *(const short8*)&xstage[8192 + off];
            p0 = MFMA(xh_, u0h[kk], p0, 0,0,0);
            p1 = MFMA(xh_, u0m[kk], p1, 0,0,0);
            p2 = MFMA(xm_, u0h[kk], p2, 0,0,0);
            p3 = MFMA(xm_, u0m[kk], p3, 0,0,0);
            p0 = MFMA(xl_, u0h[kk], p0, 0,0,0);
            if (gate == 1) {          // wave-uniform
                q0 = MFMA(xh_, u1h[kk], q0, 0,0,0);
                q1 = MFMA(xh_, u1m[kk], q1, 0,0,0);
                q2 = MFMA(xm_, u1h[kk], q2, 0,0,0);
                q3 = MFMA(xm_, u1m[kk], q3, 0,0,0);
                q0 = MFMA(xl_, u1h[kk], q0, 0,0,0);
            }
        }
        f32x4 xp0, xp1;
        #pragma unroll
        for (int r=0;r<4;++r){ xp0[r]=(p0[r]+p1[r])+(p2[r]+p3[r]); xp1[r]=(q0[r]+q1[r])+(q2[r]+q3[r]); }

        // ---- stash in LDS (C/D: row=q*4+r, col=n16) ----
        #pragma unroll
        for (int r=0;r<4;++r) {
            float v = (a0[r]+a1[r]) + (a2[r]+a3[r]);
            if (gate == 0) accC[half][q*4+r][n16] = v;
            else           accA[half][q*4+r][n16] = v;
            xpre[gate][half][q*4+r][n16] = xp0[r];
            if (gate == 1) xpre[2][half][q*4+r][n16] = xp1[r];
        }
        __syncthreads();                                   // B2

        // ---- epilogue: each wave covers (col-half wv&1, rows q*4+gate*2+e) ----
        float hn_e[2];
        #pragma unroll
        for (int e=0;e<2;++e) {
            const int row = q*4 + rp + e;
            const float cpre = accC[half][row][n16];
            const float apre = accA[half][row][n16];
            const float xc = xpre[0][half][row][n16] + bcv;
            const float xa = xpre[1][half][row][n16] + bav;
            const float xh = xpre[2][half][row][n16] + bhv;
            const int pp = wpp0 + row*8;

            float hf;
            if (t == 0)   // cur == buf0: read the init split; afterwards reg-carried
                hf = bf2f(AL16(curp+pp)) + (bf2f(AL16(curp+8192+pp)) + bf2f(AL16(curp+16384+pp)));
            else
                hf = e ? hfr1 : hfr0;

            const float cv = 1.f/(1.f + __expf(-(cpre + xc)));        // sigmoid
            const float av = 2.f/(1.f + __expf(-2.f*(apre + xa)));    // 1 + tanh
            const float zz = xh + av*hf;
            const float th = 2.f/(1.f + __expf(-2.f*zz)) - 1.f;       // tanh
            const float hn = cv*hf + (1.f - cv)*th;

            u16 sh, sm, sl; split3(hn, sh, sm, sl);
            const int ci = ((jl>>3)<<7) + row*8 + (jl&7);   // coalescing index
            hcoal[        ci] = sh;
            hcoal[ 512 +  ci] = sm;
            hcoal[1024 +  ci] = sl;
            const float hrep = bf2f(sh) + (bf2f(sm) + bf2f(sl));      // exact split-sum
            if (e) hfr1 = hrep; else hfr0 = hrep;
            hn_e[e] = hn;
        }
        // y stores (fire-and-forget HBM)
        #pragma unroll
        for (int e=0;e<2;++e) {
            const int b = b0 + q*4 + rp + e;
            __builtin_nontemporal_store(hn_e[e], &out[((size_t)t*256 + b)*512 + jme]);
            if (t == 511) out[(size_t)67108864 + (size_t)b*512 + jme] = hn_e[e];
        }
        __syncthreads();                                   // B3

        // ---- wave0: coalesced h store (3KB contiguous runs), drain, post ----
        if (wv == 0) {
            #pragma unroll
            for (int a=0; a<3; ++a) {
                union { u64 u[2]; short8 v; } w;
                w.v = *(const short8*)&hcoal[a*512 + lane*8];
                u16* d = nxtp + a*8192 + cb*512 + lane*8;
                AS64(d, w.u[0]); AS64(d+4, w.u[1]);
            }
            asm volatile("s_waitcnt vmcnt(0)" ::: "memory");
            if (lane == 0) AS32(sg + cb, (u32)t + 2u);
        }

        // ---- prefetch x(t+1); latency hides under next poll ----
        if (t < 511) {
            const float* xp = x + ((size_t)(t+1)*256 + b0 + xrow)*256 + xc0;
            xr0 = *(const f32x4*)(xp);     xr1 = *(const f32x4*)(xp+4);
            xr2 = *(const f32x4*)(xp+8);   xr3 = *(const f32x4*)(xp+12);
        }
    }
}

// ---------------- launch ----------------
extern "C" void kernel_launch(void* const* d_in, const int* in_sizes, int n_in,
                              void* d_out, int out_size, void* d_ws, size_t ws_size,
                              hipStream_t stream)
{
    (void)in_sizes; (void)n_in; (void)out_size; (void)ws_size;
    const float* x  = (const float*)d_in[0];
    const float* h0 = (const float*)d_in[1];
    const float* Uc = (const float*)d_in[2];
    const float* Wc = (const float*)d_in[3];
    const float* bc = (const float*)d_in[4];
    const float* Ua = (const float*)d_in[5];
    const float* Wa = (const float*)d_in[6];
    const float* ba = (const float*)d_in[7];
    const float* Uh = (const float*)d_in[8];
    const float* bh = (const float*)d_in[9];
    float* out = (float*)d_out;

    char* ws = (char*)d_ws;
    u32* cnt  = (u32*)ws;                                  // 16 groups x 16 slots, 128B apart
    u16* hbuf = (u16*)(ws + 2048);                         // 16 groups x 2 parity x 48KB
    // total ws use: 2048 + 16*2*24576*2B = ~1.58 MB

    hipMemsetAsync(cnt, 0, 2048, stream);                  // slots MUST start at 0

    rec_fused<<<256, 256, 0, stream>>>(x, h0, Wc, Wa, Uc, Ua, Uh, bc, ba, bh,
                                       out, hbuf, cnt);
}